// Round 3
// baseline (5983.804 us; speedup 1.0000x reference)
//
#include <hip/hip_runtime.h>
#include <hip/hip_bf16.h>

#define HH 512
#define VV 50257
#define TL 512
#define NG 4     // batch groups
#define NS 2     // column slices (blocks) per group
#define MB 16    // batches per group (full MFMA M)
#define NT 256

typedef __attribute__((ext_vector_type(8))) short short8;
typedef __attribute__((ext_vector_type(4))) float floatx4;

__device__ __forceinline__ unsigned short f2bf(float f) {
  union { float f; unsigned int u; } v; v.f = f;
  unsigned int r = (v.u + 0x7fffu + ((v.u >> 16) & 1u)) >> 16;
  return (unsigned short)r;
}

__device__ __forceinline__ float agf(const float* p) {
  return __hip_atomic_load((float*)p, __ATOMIC_RELAXED, __HIP_MEMORY_SCOPE_AGENT);
}

// ---- P1: column max of alpha_exp (+eps) and its log ----
__global__ void colmaxK(const float* __restrict__ A, float* __restrict__ cmax,
                        float* __restrict__ wmax) {
  __shared__ float red[4][64];
  int x = threadIdx.x & 63;
  int y = threadIdx.x >> 6;
  int c = blockIdx.x * 64 + x;
  float m = -INFINITY;
  for (int j = y; j < HH; j += 4) m = fmaxf(m, A[j * HH + c]);
  red[y][x] = m;
  __syncthreads();
  if (y == 0) {
    m = fmaxf(fmaxf(red[0][x], red[1][x]), fmaxf(red[2][x], red[3][x])) + 1e-12f;
    cmax[c] = m;
    wmax[c] = __logf(m);
  }
}

// ---- P2: bf16 Wn pre-swizzled into MFMA B-fragment order ----
// Wf[(T*16 + k)*64 + L] (uint4 = 8 bf16, j=0..7): Wn[32k + (L>>4)*8 + j][T*16 + (L&15)]
__global__ void buildWfK(const float* __restrict__ A, const float* __restrict__ cmax,
                         uint4* __restrict__ Wf) {
  int gid = blockIdx.x * 256 + threadIdx.x;  // 0..32767
  int T = gid >> 10;
  int k = (gid >> 6) & 15;
  int L = gid & 63;
  int n = T * 16 + (L & 15);
  int k0 = 32 * k + (L >> 4) * 8;
  float inv = 1.0f / cmax[n];
  alignas(16) unsigned short o[8];
#pragma unroll
  for (int j = 0; j < 8; ++j)
    o[j] = f2bf((A[(k0 + j) * HH + n] + 1e-12f) * inv);
  Wf[gid] = *(const uint4*)o;
}

// ---- P3: transpose beta (H,V) -> betaT (V,H), f32 ----
__global__ void transposeBeta(const float* __restrict__ beta, float* __restrict__ betaT) {
  __shared__ float tile[32][33];
  int v0 = blockIdx.x * 32, h0 = blockIdx.y * 32;
  int tx = threadIdx.x, ty = threadIdx.y;
#pragma unroll
  for (int k = 0; k < 4; ++k) {
    int v = v0 + tx;
    if (v < VV) tile[ty + 8 * k][tx] = beta[(h0 + ty + 8 * k) * VV + v];
  }
  __syncthreads();
#pragma unroll
  for (int k = 0; k < 4; ++k) {
    int v = v0 + ty + 8 * k;
    if (v < VV) betaT[(long)v * HH + h0 + tx] = tile[tx][ty + 8 * k];
  }
}

// ---- Main: 8 persistent blocks = 4 groups x 2 slices. No cache fences:
// all exchanged data uses relaxed agent-scope atomics (sc1, through to IC).
// __syncthreads drains vmcnt before the flag store => release ordering.
__global__ __launch_bounds__(NT, 1)
void hmm_main(const uint4* __restrict__ Wf,
              const float* __restrict__ wmax,
              const float* __restrict__ betaSrc, long bs1, long bs2,
              const int* __restrict__ ids,
              const float* __restrict__ gamma,
              float* __restrict__ aex,   // [2][NG][NS][MB][256]
              int* __restrict__ flags,   // [NG*NS] spaced 32 ints
              float* __restrict__ out) {
  const int g = blockIdx.x >> 1;
  const int s = blockIdx.x & 1;
  const int tid = threadIdx.x;
  const int w = tid >> 6;
  const int L = tid & 63;
  const int lane16 = L & 15;
  const int quad = L >> 4;

  __shared__ uint4 xAq[1024];        // 16 KB, fragment-ordered x tile
  __shared__ float aown[MB * 260];   // own-half alpha f32, stride 260 (b128-aligned)
  __shared__ float fm[2][4][16];     // parity x wave x row: fullrow-max partials
  __shared__ float wp[2][4][16];     // parity x wave x row: own-col rowmax partials

  // W fragments -> 256 VGPRs/lane
  short8 wreg[4][16];
#pragma unroll
  for (int nt = 0; nt < 4; ++nt)
#pragma unroll
    for (int k = 0; k < 16; ++k)
      wreg[nt][k] = __builtin_bit_cast(short8, Wf[((s * 16 + w * 4 + nt) * 16 + k) * 64 + L]);

  float wmaxv[4];
#pragma unroll
  for (int nt = 0; nt < 4; ++nt) wmaxv[nt] = wmax[s * 256 + w * 64 + nt * 16 + lane16];

  int* myflag = &flags[(g * NS + s) * 32];
  int* peerflag = &flags[(g * NS + (1 - s)) * 32];
  const int myk0 = s * 8, pk0 = (1 - s) * 8;

  // ---- t = 0 init: thread = (row = tid&15, col-block cb = tid>>4) ----
  {
    const int row = tid & 15;
    const int cb = tid >> 4;
    const int id0 = ids[(g * MB + row) * TL];
    float mx = -INFINITY, vals[16];
#pragma unroll
    for (int j = 0; j < 16; ++j) {
      int cl = cb * 16 + j, col = s * 256 + cl;
      float a = __logf(gamma[col]) + betaSrc[(long)id0 * bs1 + (long)col * bs2];
      vals[j] = a; mx = fmaxf(mx, a);
      aown[row * 260 + cl] = a;
    }
    float* dst = aex + (((0 * NG + g) * NS + s) * MB + row) * 256;
#pragma unroll
    for (int j = 0; j < 16; ++j)
      __hip_atomic_store(&dst[cb * 16 + j], vals[j], __ATOMIC_RELAXED, __HIP_MEMORY_SCOPE_AGENT);
    mx = fmaxf(mx, __shfl_xor(mx, 16));
    mx = fmaxf(mx, __shfl_xor(mx, 32));
    if (quad == 0) { fm[0][w][lane16] = mx; wp[0][w][lane16] = mx; }
  }
  __syncthreads();  // drains vmcnt(0): init stores visible before flag
  if (tid == 0)
    __hip_atomic_store(myflag, 1, __ATOMIC_RELAXED, __HIP_MEMORY_SCOPE_AGENT);

  for (int t = 1; t < TL; ++t) {
    const int pr = (t - 1) & 1, pw = t & 1;
    const int row = tid & 15;
    const int kk = tid >> 4;               // global 32-col chunk = MFMA k-step
    const bool own = (kk >> 3) == s;

    // Phase P: beta gather prefetch for epilogue (rows quad*4+i, cols of this lane)
    float betav[4][4];
#pragma unroll
    for (int i = 0; i < 4; ++i) {
      int id = ids[(g * MB + quad * 4 + i) * TL + t];
#pragma unroll
      for (int nt = 0; nt < 4; ++nt)
        betav[nt][i] = betaSrc[(long)id * bs1 + (long)(s * 256 + w * 64 + nt * 16 + lane16) * bs2];
    }

    // block-local shift for my pack-row (deterministic: parity-stable fm/wp)
    float mest = -INFINITY;
#pragma unroll
    for (int j = 0; j < 4; ++j) mest = fmaxf(mest, fmaxf(fm[pr][j][row], wp[pr][j][row]));

    float fmx = -INFINITY;
    if (own) {  // pack own half from LDS (alpha_{t-1} own cols)
      const int cl0 = kk * 32 - s * 256;
      alignas(16) unsigned short xv[32];
#pragma unroll
      for (int jj = 0; jj < 8; ++jj) {
        float4 v = *(const float4*)&aown[row * 260 + cl0 + jj * 4];
        float a4[4] = {v.x, v.y, v.z, v.w};
#pragma unroll
        for (int e = 0; e < 4; ++e) {
          fmx = fmaxf(fmx, a4[e]);
          xv[jj * 4 + e] = f2bf(__expf(a4[e] - mest));
        }
      }
#pragma unroll
      for (int q = 0; q < 4; ++q)
        xAq[kk * 64 + q * 16 + row] = *(const uint4*)&xv[q * 8];
    }
    __syncthreads();  // sync1: own chunks in xAq

    // Phase C1: MFMA over own k (overlaps peer's flag/data latency)
    floatx4 acc[4];
#pragma unroll
    for (int nt = 0; nt < 4; ++nt) acc[nt] = (floatx4){0.f, 0.f, 0.f, 0.f};
#pragma unroll
    for (int k = 0; k < 8; ++k) {
      int kg = myk0 + k;
      short8 af = __builtin_bit_cast(short8, xAq[kg * 64 + L]);
#pragma unroll
      for (int nt = 0; nt < 4; ++nt)
        acc[nt] = __builtin_amdgcn_mfma_f32_16x16x32_bf16(af, wreg[nt][kg], acc[nt], 0, 0, 0);
    }

    // Phase W+R: peer-chunk threads poll, fetch, exp, pack
    if (!own) {
      int spin = 0;
      while (__hip_atomic_load(peerflag, __ATOMIC_RELAXED, __HIP_MEMORY_SCOPE_AGENT) < t) {
        if (++spin > (1 << 17)) break;  // valve: corrupt, not hung
      }
      const int off = kk * 32 - (1 - s) * 256;
      unsigned long long* src = (unsigned long long*)
          (aex + (((pr * NG + g) * NS + (1 - s)) * MB + row) * 256 + off);
      float av[32];
#pragma unroll
      for (int j = 0; j < 16; ++j) {
        unsigned long long u =
            __hip_atomic_load(&src[j], __ATOMIC_RELAXED, __HIP_MEMORY_SCOPE_AGENT);
        union { unsigned long long u; float f[2]; } cc; cc.u = u;
        av[2 * j] = cc.f[0]; av[2 * j + 1] = cc.f[1];
      }
      alignas(16) unsigned short xv[32];
#pragma unroll
      for (int j = 0; j < 32; ++j) {
        fmx = fmaxf(fmx, av[j]);
        xv[j] = f2bf(__expf(av[j] - mest));
      }
#pragma unroll
      for (int q = 0; q < 4; ++q)
        xAq[kk * 64 + q * 16 + row] = *(const uint4*)&xv[q * 8];
    }
    // fullrow-max(alpha_{t-1}) partial per wave (wave-uniform own/peer)
    fmx = fmaxf(fmx, __shfl_xor(fmx, 16));
    fmx = fmaxf(fmx, __shfl_xor(fmx, 32));
    if (quad == 0) fm[pw][w][lane16] = fmx;
    __syncthreads();  // sync2: peer chunks in xAq

    // Phase C2: MFMA over peer k
#pragma unroll
    for (int k = 0; k < 8; ++k) {
      int kg = pk0 + k;
      short8 af = __builtin_bit_cast(short8, xAq[kg * 64 + L]);
#pragma unroll
      for (int nt = 0; nt < 4; ++nt)
        acc[nt] = __builtin_amdgcn_mfma_f32_16x16x32_bf16(af, wreg[nt][kg], acc[nt], 0, 0, 0);
    }

    // Phase D: epilogue. alpha = log z + mest(row) + wmax + beta
    float anew[4][4];
#pragma unroll
    for (int i = 0; i < 4; ++i) {
      int r = quad * 4 + i;
      float me = -INFINITY;
#pragma unroll
      for (int j = 0; j < 4; ++j) me = fmaxf(me, fmaxf(fm[pr][j][r], wp[pr][j][r]));
#pragma unroll
      for (int nt = 0; nt < 4; ++nt)
        anew[nt][i] = __logf(fmaxf(acc[nt][i], 1e-37f)) + me + wmaxv[nt] + betav[nt][i];
    }
    float rm[4];
#pragma unroll
    for (int i = 0; i < 4; ++i) {
      float m = fmaxf(fmaxf(anew[0][i], anew[1][i]), fmaxf(anew[2][i], anew[3][i]));
#pragma unroll
      for (int msk = 1; msk <= 8; msk <<= 1) m = fmaxf(m, __shfl_xor(m, msk));
      rm[i] = m;
    }
    if (lane16 == 0)
#pragma unroll
      for (int i = 0; i < 4; ++i) wp[pw][w][quad * 4 + i] = rm[i];

    // Phase E: publish alpha_t (LDS + IC) and flag
    float* dstL = aex + (((pw * NG + g) * NS + s) * MB) * 256;
#pragma unroll
    for (int i = 0; i < 4; ++i) {
      int r = quad * 4 + i;
#pragma unroll
      for (int nt = 0; nt < 4; ++nt) {
        int cl = w * 64 + nt * 16 + lane16;
        aown[r * 260 + cl] = anew[nt][i];
        __hip_atomic_store(&dstL[r * 256 + cl], anew[nt][i],
                           __ATOMIC_RELAXED, __HIP_MEMORY_SCOPE_AGENT);
      }
    }
    if (t == TL - 1) {
#pragma unroll
      for (int i = 0; i < 4; ++i)
#pragma unroll
        for (int nt = 0; nt < 4; ++nt)
          out[(g * MB + quad * 4 + i) * HH + s * 256 + w * 64 + nt * 16 + lane16] = anew[nt][i];
    }
    __syncthreads();  // Esync: vmcnt(0) drained -> release
    if (tid == 0)
      __hip_atomic_store(myflag, t + 1, __ATOMIC_RELAXED, __HIP_MEMORY_SCOPE_AGENT);
  }
}

extern "C" void kernel_launch(void* const* d_in, const int* in_sizes, int n_in,
                              void* d_out, int out_size, void* d_ws, size_t ws_size,
                              hipStream_t stream) {
  const float* alpha_exp = (const float*)d_in[0];
  const float* beta = (const float*)d_in[1];
  const float* gamma = (const float*)d_in[2];
  const int* ids = (const int*)d_in[3];
  float* out = (float*)d_out;

  char* ws = (char*)d_ws;
  float* cmax  = (float*)(ws + 0);        // 2 KB
  float* wmax  = (float*)(ws + 2048);     // 2 KB
  uint4* Wf    = (uint4*)(ws + 4096);     // 512 KB -> ends 528384
  float* aex   = (float*)(ws + 528384);   // 2*4*2*16*256*4 = 256 KB -> ends 790528
  int*   flags = (int*)(ws + 790528);     // 8*32*4 = 1 KB -> ends 791552 (0xAA poison < 1: safe)
  float* betaT = (float*)(ws + 792576);   // 102.9 MB (optional)
  const size_t need_full = 792576ull + (size_t)VV * HH * 4ull;

  colmaxK<<<8, 256, 0, stream>>>(alpha_exp, cmax, wmax);
  buildWfK<<<128, 256, 0, stream>>>(alpha_exp, cmax, Wf);

  const float* betaSrc;
  long bs1, bs2;
  if (ws_size >= need_full) {
    dim3 gT((VV + 31) / 32, HH / 32), bT(32, 8);
    transposeBeta<<<gT, bT, 0, stream>>>(beta, betaT);
    betaSrc = betaT; bs1 = HH; bs2 = 1;
  } else {
    betaSrc = beta; bs1 = 1; bs2 = VV;
  }

  hmm_main<<<NG * NS, NT, 0, stream>>>(Wf, wmax, betaSrc, bs1, bs2, ids, gamma,
                                       aex, flags, out);
}

// Round 4
// 1946.499 us; speedup vs baseline: 3.0741x; 3.0741x over previous
//
#include <hip/hip_runtime.h>
#include <hip/hip_bf16.h>

#define HH 512
#define VV 50257
#define TL 512
#define NT 512   // 8 waves per block, one block per batch

typedef __attribute__((ext_vector_type(8))) short short8;
typedef __attribute__((ext_vector_type(4))) float floatx4;

__device__ __forceinline__ unsigned short f2bf(float f) {
  union { float f; unsigned int u; } v; v.f = f;
  unsigned int r = (v.u + 0x7fffu + ((v.u >> 16) & 1u)) >> 16;
  return (unsigned short)r;
}

// ---- P1: column max of alpha_exp (+eps) ----
__global__ void colmaxK(const float* __restrict__ A, float* __restrict__ cmax) {
  __shared__ float red[4][64];
  int x = threadIdx.x & 63;
  int y = threadIdx.x >> 6;
  int c = blockIdx.x * 64 + x;
  float m = -INFINITY;
  for (int j = y; j < HH; j += 4) m = fmaxf(m, A[j * HH + c]);
  red[y][x] = m;
  __syncthreads();
  if (y == 0)
    cmax[c] = fmaxf(fmaxf(red[0][x], red[1][x]), fmaxf(red[2][x], red[3][x])) + 1e-12f;
}

// ---- P2: bf16 Wn pre-swizzled into MFMA B-fragment order ----
// Wf[(T*16 + k)*64 + L] (uint4 = 8 bf16, j=0..7): Wn[32k + (L>>4)*8 + j][T*16 + (L&15)]
__global__ void buildWfK(const float* __restrict__ A, const float* __restrict__ cmax,
                         uint4* __restrict__ Wf) {
  int gid = blockIdx.x * 256 + threadIdx.x;  // 0..32767
  int T = gid >> 10;
  int k = (gid >> 6) & 15;
  int L = gid & 63;
  int n = T * 16 + (L & 15);
  int k0 = 32 * k + (L >> 4) * 8;
  float inv = 1.0f / cmax[n];
  alignas(16) unsigned short o[8];
#pragma unroll
  for (int j = 0; j < 8; ++j)
    o[j] = f2bf((A[(k0 + j) * HH + n] + 1e-12f) * inv);
  Wf[gid] = *(const uint4*)o;
}

// ---- P3: Ptab[v][n] = exp(beta[n][v]) * cmax[n]  (fused transpose+exp+scale) ----
__global__ void buildPtab(const float* __restrict__ beta, const float* __restrict__ cmax,
                          float* __restrict__ Ptab) {
  __shared__ float tile[32][33];
  int v0 = blockIdx.x * 32, h0 = blockIdx.y * 32;
  int tx = threadIdx.x, ty = threadIdx.y;
#pragma unroll
  for (int k = 0; k < 4; ++k) {
    int v = v0 + tx;
    if (v < VV) tile[ty + 8 * k][tx] = beta[(h0 + ty + 8 * k) * VV + v];
  }
  __syncthreads();
  float cm = cmax[h0 + tx];
#pragma unroll
  for (int k = 0; k < 4; ++k) {
    int v = v0 + ty + 8 * k;
    if (v < VV) Ptab[(long)v * HH + h0 + tx] = __expf(tile[tx][ty + 8 * k]) * cm;
  }
}

// ---- Main: 64 fully independent blocks (one per batch). No global scratch,
// no inter-block sync. x lives in LDS (bf16, double-buffered); W in VGPRs.
// Scale bookkeeping: y_t = u_t / G_t with G_t = max u_{t-1} (stale, bounded
// oscillation since it's a ratio of consecutive maxima); A_t = A_{t-1} + log G_t;
// alpha_T[n] = log(u_T[n]) + A_{T-1}. cmax/wmax absorbed into Ptab.
__global__ __launch_bounds__(NT, 1)
void hmm_main(const uint4* __restrict__ Wf,
              const float* __restrict__ Ptab,
              const float* __restrict__ beta,   // fallback when mode==0
              const float* __restrict__ gamma,
              const float* __restrict__ cmax,
              const int* __restrict__ ids,
              float* __restrict__ out, int mode) {
  const int b = blockIdx.x;
  const int tid = threadIdx.x;
  const int w = tid >> 6;        // wave 0..7, owns n in [64w, 64w+64)
  const int L = tid & 63;
  const int quad = L >> 4;
  const int n = w * 64 + L;      // this lane's output column
  const long bT = (long)b * TL;

  __shared__ unsigned short xbuf[2][HH];  // bf16 y, double-buffered
  __shared__ float wmx[2][8];             // per-wave u-max partials
  __shared__ int ids_l[TL];

  // W fragments: wave w owns n-tiles 4w..4w+3 -> 256 VGPRs/lane
  short8 wreg[4][16];
#pragma unroll
  for (int tau = 0; tau < 4; ++tau)
#pragma unroll
    for (int k = 0; k < 16; ++k)
      wreg[tau][k] = __builtin_bit_cast(short8, Wf[((w * 4 + tau) * 16 + k) * 64 + L]);

  const float cmx = cmax[n];

  // all ids for this batch -> LDS (2 KB)
  ids_l[tid] = ids[bT + tid];

  // ---- t = 0 ----
  int id0 = ids[bT];
  float P0 = mode ? Ptab[(long)id0 * HH + n] : __expf(beta[(long)n * VV + id0]) * cmx;
  float u = gamma[n] * P0 / cmx;  // = gamma * exp(beta)
  {
    float m = u;
#pragma unroll
    for (int msk = 1; msk <= 32; msk <<= 1) m = fmaxf(m, __shfl_xor(m, msk));
    if (L == 0) wmx[0][w] = m;
  }
  __syncthreads();  // publish wmx[0], ids_l
  float A;
  {
    float4 q0 = *(const float4*)&wmx[0][0];
    float4 q1 = *(const float4*)&wmx[0][4];
    float M = fmaxf(fmaxf(fmaxf(q0.x, q0.y), fmaxf(q0.z, q0.w)),
                    fmaxf(fmaxf(q1.x, q1.y), fmaxf(q1.z, q1.w)));
    A = __logf(M);
    xbuf[0][n] = f2bf(u / M);
  }
  __syncthreads();  // publish xbuf[0]

  for (int t = 1; t < TL; ++t) {
    const int pr = (t - 1) & 1, pw = t & 1;

    // prefetch P[id_t][n] (consumed ~700 cy later at epilogue; syncthreads
    // at loop end is the only vmcnt(0) drain, so it stays in flight past MFMA)
    const int idt = ids_l[t];
    const float pv = mode ? Ptab[(long)idt * HH + n]
                          : beta[(long)n * VV + idt];

    // stale global max of u_{t-1} -> scale for y_t
    float4 q0 = *(const float4*)&wmx[pr][0];
    float4 q1 = *(const float4*)&wmx[pr][4];
    float G = fmaxf(fmaxf(fmaxf(q0.x, q0.y), fmaxf(q0.z, q0.w)),
                    fmaxf(fmaxf(q1.x, q1.y), fmaxf(q1.z, q1.w)));
    float r = 1.0f / G;

    // MFMA: A-frag = broadcast reads of the single y row (replicated over m)
    floatx4 acc[4];
#pragma unroll
    for (int tau = 0; tau < 4; ++tau) acc[tau] = (floatx4){0.f, 0.f, 0.f, 0.f};
    short8 afr[16];
#pragma unroll
    for (int kk = 0; kk < 16; ++kk)
      afr[kk] = *(const short8*)&xbuf[pr][kk * 32 + quad * 8];
#pragma unroll
    for (int kk = 0; kk < 16; ++kk)
#pragma unroll
      for (int tau = 0; tau < 4; ++tau)
        acc[tau] = __builtin_amdgcn_mfma_f32_16x16x32_bf16(afr[kk], wreg[tau][kk],
                                                           acc[tau], 0, 0, 0);

    // epilogue: rows are replicated -> each lane takes tile=quad, reg 0
    float z = quad == 0 ? acc[0][0] : quad == 1 ? acc[1][0]
            : quad == 2 ? acc[2][0] : acc[3][0];
    float P = mode ? pv : __expf(pv) * cmx;
    float un = z * P;  // u_t[n]
    if (t == TL - 1) {
      out[(long)b * HH + n] = __logf(fmaxf(un, 1e-37f)) + A;
    } else {
      A += __logf(G);
      float m = un;
#pragma unroll
      for (int msk = 1; msk <= 32; msk <<= 1) m = fmaxf(m, __shfl_xor(m, msk));
      if (L == 0) wmx[pw][w] = m;
      xbuf[pw][n] = f2bf(un * r);
    }
    __syncthreads();
  }
}

extern "C" void kernel_launch(void* const* d_in, const int* in_sizes, int n_in,
                              void* d_out, int out_size, void* d_ws, size_t ws_size,
                              hipStream_t stream) {
  const float* alpha_exp = (const float*)d_in[0];
  const float* beta = (const float*)d_in[1];
  const float* gamma = (const float*)d_in[2];
  const int* ids = (const int*)d_in[3];
  float* out = (float*)d_out;

  char* ws = (char*)d_ws;
  float* cmax = (float*)(ws + 0);        // [0, 2048)
  uint4* Wf   = (uint4*)(ws + 4096);     // [4096, 528384)  512 KB
  float* Ptab = (float*)(ws + 528384);   // 102.9 MB (optional)
  const size_t need_full = 528384ull + (size_t)VV * HH * 4ull;
  const int mode = (ws_size >= need_full) ? 1 : 0;

  colmaxK<<<8, 256, 0, stream>>>(alpha_exp, cmax);
  buildWfK<<<128, 256, 0, stream>>>(alpha_exp, cmax, Wf);
  if (mode) {
    dim3 gT((VV + 31) / 32, HH / 32), bT(32, 8);
    buildPtab<<<gT, bT, 0, stream>>>(beta, cmax, Ptab);
  }

  hmm_main<<<64, NT, 0, stream>>>(Wf, Ptab, beta, gamma, cmax, ids, out, mode);
}

// Round 5
// 1630.530 us; speedup vs baseline: 3.6699x; 1.1938x over previous
//
#include <hip/hip_runtime.h>
#include <hip/hip_bf16.h>

#define HH 512
#define VV 50257
#define TL 512
#define NT 256          // 4 waves; 64 blocks, one batch per block
#define KREG 12         // k-tiles (of 16) pinned in AGPRs: 8 tiles x 12 x 4 = 384 AGPR/lane
#define KLDS 4          // k-tiles resident in LDS: 4 x 32 KB = 128 KB
#define DYN_LDS 135200

typedef __attribute__((ext_vector_type(8))) short short8;
typedef __attribute__((ext_vector_type(4))) float floatx4;

__device__ __forceinline__ unsigned short f2bf(float f) {
  union { float f; unsigned int u; } v; v.f = f;
  unsigned int r = (v.u + 0x7fffu + ((v.u >> 16) & 1u)) >> 16;
  return (unsigned short)r;
}
__device__ __forceinline__ float bf2f(unsigned short h) {
  union { unsigned int u; float f; } v; v.u = ((unsigned int)h) << 16;
  return v.f;
}

// ---- P1: column max of alpha_exp (+eps) ----
__global__ void colmaxK(const float* __restrict__ A, float* __restrict__ cmax) {
  __shared__ float red[4][64];
  int x = threadIdx.x & 63;
  int y = threadIdx.x >> 6;
  int c = blockIdx.x * 64 + x;
  float m = -INFINITY;
  for (int j = y; j < HH; j += 4) m = fmaxf(m, A[j * HH + c]);
  red[y][x] = m;
  __syncthreads();
  if (y == 0)
    cmax[c] = fmaxf(fmaxf(red[0][x], red[1][x]), fmaxf(red[2][x], red[3][x])) + 1e-12f;
}

// ---- P2: bf16 Wn pre-swizzled into MFMA B-fragment order ----
// Wf[(T*16 + k)*64 + L] (uint4 = 8 bf16, j=0..7): Wn[32k + (L>>4)*8 + j][T*16 + (L&15)]
__global__ void buildWfK(const float* __restrict__ A, const float* __restrict__ cmax,
                         uint4* __restrict__ Wf) {
  int gid = blockIdx.x * 256 + threadIdx.x;  // 0..32767
  int T = gid >> 10;
  int k = (gid >> 6) & 15;
  int L = gid & 63;
  int n = T * 16 + (L & 15);
  int k0 = 32 * k + (L >> 4) * 8;
  float inv = 1.0f / cmax[n];
  alignas(16) unsigned short o[8];
#pragma unroll
  for (int j = 0; j < 8; ++j)
    o[j] = f2bf((A[(k0 + j) * HH + n] + 1e-12f) * inv);
  Wf[gid] = *(const uint4*)o;
}

// ---- P3: Ptab[v][n] = bf16( exp(beta[n][v]) * cmax[n] ) ----
__global__ void buildPtab(const float* __restrict__ beta, const float* __restrict__ cmax,
                          unsigned short* __restrict__ Ptab) {
  __shared__ float tile[32][33];
  int v0 = blockIdx.x * 32, h0 = blockIdx.y * 32;
  int tx = threadIdx.x, ty = threadIdx.y;
#pragma unroll
  for (int k = 0; k < 4; ++k) {
    int v = v0 + tx;
    if (v < VV) tile[ty + 8 * k][tx] = beta[(h0 + ty + 8 * k) * VV + v];
  }
  __syncthreads();
  float cm = cmax[h0 + tx];
#pragma unroll
  for (int k = 0; k < 4; ++k) {
    int v = v0 + ty + 8 * k;
    if (v < VV) Ptab[(long)v * HH + h0 + tx] = f2bf(__expf(tile[tx][ty + 8 * k]) * cm);
  }
}

// ---- Main: 64 independent blocks (one batch each), 4 waves. W: 384 AGPR/lane
// (asm-pinned) + 128 KB LDS. y row in LDS bf16; linear recurrence with stale-max
// rescale (R4-verified): u_t = z_t*P_t ; y_t = u_t/G ; A += log G.
__global__ __launch_bounds__(NT) __attribute__((amdgpu_waves_per_eu(1, 1)))
void hmm_main(const uint4* __restrict__ Wf,
              const unsigned short* __restrict__ Ptab,
              const float* __restrict__ gamma,
              const float* __restrict__ cmax,
              const int* __restrict__ ids,
              float* __restrict__ out) {
  extern __shared__ char dls[];
  uint4* wlds = (uint4*)dls;                               // [0, 131072)
  unsigned short* xbuf = (unsigned short*)(dls + 131072);  // [2][512] bf16
  int* ids_l = (int*)(dls + 133120);                       // [512]
  float* wmx = (float*)(dls + 135168);                     // [2][4]

  const int b = blockIdx.x, tid = threadIdx.x;
  const int w = tid >> 6, L = tid & 63;
  const int l16 = L & 15, q = L >> 4;
  const long bT = (long)b * TL;

  ids_l[tid] = ids[bT + tid];
  ids_l[tid + 256] = ids[bT + tid + 256];

  // stage LDS-resident W k-tiles 12..15 (layout == read order: base + lane*16)
#pragma unroll
  for (int i = 0; i < 32; ++i) {
    int e = tid + i * 256;            // 0..8191
    int Le = e & 63, r = e >> 6;      // r: kk*32 + T
    int T = r & 31, kk = r >> 5;
    wlds[e] = Wf[(T * 16 + KREG + kk) * 64 + Le];
  }

  // AGPR-pinned W: wave w owns n-tiles T = 8w+tau, tau=0..7
  short8 wreg[8][KREG];
#pragma unroll
  for (int tau = 0; tau < 8; ++tau)
#pragma unroll
    for (int k = 0; k < KREG; ++k)
      wreg[tau][k] = __builtin_bit_cast(short8, Wf[((8 * w + tau) * 16 + k) * 64 + L]);

  // this lane's two output columns: tiles 2q, 2q+1 at col l16
  const int n0 = 128 * w + 32 * q + l16;
  const int n1 = n0 + 16;

  // ---- t = 0 ----
  float A;
  {
    const int id0 = ids[bT];
    float u0 = gamma[n0] * bf2f(Ptab[(long)id0 * HH + n0]) / cmax[n0];
    float u1 = gamma[n1] * bf2f(Ptab[(long)id0 * HH + n1]) / cmax[n1];
    float m = fmaxf(u0, u1);
#pragma unroll
    for (int msk = 1; msk <= 32; msk <<= 1) m = fmaxf(m, __shfl_xor(m, msk));
    if (L == 0) wmx[w] = m;
    __syncthreads();
    float4 gq = *(const float4*)&wmx[0];
    float M = fmaxf(fmaxf(gq.x, gq.y), fmaxf(gq.z, gq.w));
    A = __logf(M);
    xbuf[n0] = f2bf(u0 / M);
    xbuf[n1] = f2bf(u1 / M);
    __syncthreads();
  }

  for (int t = 1; t < TL; ++t) {
    const int pr = (t - 1) & 1, pw = t & 1;
    const int idt = ids_l[t];
    const unsigned short pv0 = Ptab[(long)idt * HH + n0];  // prefetch, consumed at epilogue
    const unsigned short pv1 = Ptab[(long)idt * HH + n1];

    float4 gq = *(const float4*)&wmx[pr * 4];
    float G = fmaxf(fmaxf(gq.x, gq.y), fmaxf(gq.z, gq.w));
    float rG = 1.0f / G;

    floatx4 acc[8];
#pragma unroll
    for (int tau = 0; tau < 8; ++tau) acc[tau] = (floatx4){0.f, 0.f, 0.f, 0.f};

    const unsigned short* xb = xbuf + pr * 512;
#pragma unroll
    for (int k = 0; k < KREG; ++k) {
      short8 af = *(const short8*)(xb + k * 32 + q * 8);  // quad-broadcast, replicated rows
#pragma unroll
      for (int tau = 0; tau < 8; ++tau)
        asm("v_mfma_f32_16x16x32_bf16 %0, %1, %2, %0"
            : "+a"(acc[tau]) : "v"(af), "a"(wreg[tau][k]));
    }
#pragma unroll
    for (int kk = 0; kk < KLDS; ++kk) {
      short8 af = *(const short8*)(xb + (KREG + kk) * 32 + q * 8);
#pragma unroll
      for (int tau = 0; tau < 8; ++tau) {
        short8 wl = __builtin_bit_cast(short8, wlds[(kk * 32 + 8 * w + tau) * 64 + L]);
        acc[tau] = __builtin_amdgcn_mfma_f32_16x16x32_bf16(af, wl, acc[tau], 0, 0, 0);
      }
    }

    float z0 = (q < 2) ? (q == 0 ? acc[0][0] : acc[2][0])
                       : (q == 2 ? acc[4][0] : acc[6][0]);
    float z1 = (q < 2) ? (q == 0 ? acc[1][0] : acc[3][0])
                       : (q == 2 ? acc[5][0] : acc[7][0]);
    float un0 = z0 * bf2f(pv0);
    float un1 = z1 * bf2f(pv1);

    if (t == TL - 1) {
      out[(long)b * HH + n0] = __logf(fmaxf(un0, 1e-37f)) + A;
      out[(long)b * HH + n1] = __logf(fmaxf(un1, 1e-37f)) + A;
    } else {
      A += __logf(G);
      float m = fmaxf(un0, un1);
#pragma unroll
      for (int msk = 1; msk <= 32; msk <<= 1) m = fmaxf(m, __shfl_xor(m, msk));
      if (L == 0) wmx[pw * 4 + w] = m;
      xbuf[pw * 512 + n0] = f2bf(un0 * rG);
      xbuf[pw * 512 + n1] = f2bf(un1 * rG);
    }
    __syncthreads();
  }
}

extern "C" void kernel_launch(void* const* d_in, const int* in_sizes, int n_in,
                              void* d_out, int out_size, void* d_ws, size_t ws_size,
                              hipStream_t stream) {
  const float* alpha_exp = (const float*)d_in[0];
  const float* beta = (const float*)d_in[1];
  const float* gamma = (const float*)d_in[2];
  const int* ids = (const int*)d_in[3];
  float* out = (float*)d_out;

  char* ws = (char*)d_ws;
  float* cmax = (float*)(ws + 0);                    // [0, 2048)
  uint4* Wf = (uint4*)(ws + 4096);                   // [4096, 528384)
  unsigned short* Ptab = (unsigned short*)(ws + 528384);  // 51.5 MB (ws proven >= 104 MB)

  // idempotent, host-side (not a stream op; graph-capture safe), every call:
  (void)hipFuncSetAttribute((const void*)hmm_main,
                            hipFuncAttributeMaxDynamicSharedMemorySize, DYN_LDS);

  colmaxK<<<8, 256, 0, stream>>>(alpha_exp, cmax);
  buildWfK<<<128, 256, 0, stream>>>(alpha_exp, cmax, Wf);
  dim3 gT((VV + 31) / 32, HH / 32), bT(32, 8);
  buildPtab<<<gT, bT, 0, stream>>>(beta, cmax, Ptab);

  hmm_main<<<64, NT, DYN_LDS, stream>>>(Wf, Ptab, gamma, cmax, ids, out);
}